// Round 2
// baseline (448.008 us; speedup 1.0000x reference)
//
#include <hip/hip_runtime.h>
#include <hip/hip_bf16.h>
#include <cstdint>
#include <cstddef>

// Problem constants (fixed by reference)
#define BROWS   16384
#define LDIM    128
#define HDIM    512
#define KDIM    1152            // LABEL_DIM + 2*H_DIM
#define NGATES  2560            // 5 * HDIM  (i, o, u, f0, f1)

// workspace layout (bytes)
#define XB_BYTES  ((size_t)BROWS * KDIM * 2)            // 37,748,736
#define WB_BYTES  ((size_t)NGATES * KDIM * 2)           //  5,898,240

using f32x4   = __attribute__((ext_vector_type(4))) float;
using bfrag   = __attribute__((ext_vector_type(8))) short;   // 8 bf16 = 4 VGPRs
using short4v = __attribute__((ext_vector_type(4))) short;

__device__ __forceinline__ short f2bf(float f) {
    union { float f; uint32_t u; } a; a.f = f;
    uint32_t u = a.u;
    uint32_t lsb = (u >> 16) & 1u;
    u += 0x7fffu + lsb;               // round-to-nearest-even
    return (short)(u >> 16);
}

__device__ __forceinline__ void load_lds16(const void* g, void* l) {
    __builtin_amdgcn_global_load_lds(
        (const __attribute__((address_space(1))) void*)g,
        (__attribute__((address_space(3))) void*)l, 16, 0, 0);
}

__device__ __forceinline__ float fast_sigmoid(float x) {
    return 1.0f / (1.0f + __expf(-x));
}
__device__ __forceinline__ float fast_tanh(float x) {
    // stable at both tails: exp(2x)->inf gives 1, ->0 gives -1
    float t = __expf(2.0f * x);
    return 1.0f - 2.0f / (t + 1.0f);
}

// ---------------------------------------------------------------------------
// pack_x: xb[b, 0:128] = label[b,:]; xb[b, 128 + k*512 + j] = children_h[k,b,j]
// ---------------------------------------------------------------------------
__global__ __launch_bounds__(256) void pack_x(const float* __restrict__ label,
                                              const float* __restrict__ chh,
                                              short* __restrict__ xb) {
    const int perRow = KDIM / 4;  // 288
    int tid = blockIdx.x * 256 + threadIdx.x;
    int b  = tid / perRow;
    int d4 = (tid - b * perRow) * 4;
    if (b >= BROWS) return;
    float4 v;
    if (d4 < LDIM) {
        v = *(const float4*)(label + (size_t)b * LDIM + d4);
    } else {
        int dd = d4 - LDIM;
        int k  = dd >> 9;           // child index
        int j  = dd & 511;
        v = *(const float4*)(chh + ((size_t)k * BROWS + b) * HDIM + j);
    }
    short4v s;
    s.x = f2bf(v.x); s.y = f2bf(v.y); s.z = f2bf(v.z); s.w = f2bf(v.w);
    *(short4v*)(xb + (size_t)b * KDIM + d4) = s;
}

// ---------------------------------------------------------------------------
// pack_w: Wb row n (0..2559), K-contiguous bf16.
//   g = n>>9: 0->W_i, 1->W_o, 2->W_u, 3->Wf0, 4->Wf1
//   Wf_k row h = [ W_fl[h,:] (128) | W_fs[k,0,h,:] (512) | W_fs[k,1,h,:] (512) ]
// ---------------------------------------------------------------------------
__global__ __launch_bounds__(256) void pack_w(const float* __restrict__ Wi,
                                              const float* __restrict__ Wo,
                                              const float* __restrict__ Wu,
                                              const float* __restrict__ Wfl,
                                              const float* __restrict__ Wfs,
                                              short* __restrict__ Wb) {
    const int perRow = KDIM / 4;  // 288
    int tid = blockIdx.x * 256 + threadIdx.x;
    int n  = tid / perRow;
    int d4 = (tid - n * perRow) * 4;
    if (n >= NGATES) return;
    int g = n >> 9, h = n & 511;
    const float* src;
    if (g == 0)      src = Wi + (size_t)h * KDIM + d4;
    else if (g == 1) src = Wo + (size_t)h * KDIM + d4;
    else if (g == 2) src = Wu + (size_t)h * KDIM + d4;
    else {
        int k = g - 3;
        if (d4 < LDIM) {
            src = Wfl + (size_t)h * LDIM + d4;
        } else {
            int dd = d4 - LDIM;
            int j  = dd >> 9;
            int jj = dd & 511;
            src = Wfs + (((size_t)(k * 2 + j) * HDIM + h) * HDIM) + jj;
        }
    }
    float4 v = *(const float4*)src;
    short4v s;
    s.x = f2bf(v.x); s.y = f2bf(v.y); s.z = f2bf(v.z); s.w = f2bf(v.w);
    *(short4v*)(Wb + (size_t)n * KDIM + d4) = s;
}

// ---------------------------------------------------------------------------
// one 128x128 sub-GEMM pass (m97 structure): acc = A_tile * B_tile^T
// ---------------------------------------------------------------------------
__device__ __forceinline__ void run_gemm_pass(
    const short* __restrict__ Arow0, const short* __restrict__ Arow1,
    const short* __restrict__ Brow0, const short* __restrict__ Brow1,
    short* As, short* Bs,
    int s0, int s1, int wr, int wc, int quad, int l16,
    f32x4 acc[4][4])
{
#pragma unroll
    for (int i = 0; i < 4; ++i)
#pragma unroll
        for (int j = 0; j < 4; ++j)
            acc[i][j] = (f32x4){0.f, 0.f, 0.f, 0.f};

    for (int k0 = 0; k0 < KDIM; k0 += 32) {
        load_lds16(Arow0 + k0, As + s0 * 8);
        load_lds16(Arow1 + k0, As + s1 * 8);
        load_lds16(Brow0 + k0, Bs + s0 * 8);
        load_lds16(Brow1 + k0, Bs + s1 * 8);
        __syncthreads();

        bfrag a[4], b[4];
#pragma unroll
        for (int i = 0; i < 4; ++i) {
            a[i] = *(const bfrag*)(As + (wr * 64 + i * 16 + l16) * 32 + quad * 8);
            b[i] = *(const bfrag*)(Bs + (wc * 64 + i * 16 + l16) * 32 + quad * 8);
        }
#pragma unroll
        for (int i = 0; i < 4; ++i)
#pragma unroll
            for (int j = 0; j < 4; ++j)
                acc[i][j] = __builtin_amdgcn_mfma_f32_16x16x32_bf16(a[i], b[j], acc[i][j], 0, 0, 0);
        __syncthreads();
    }
}

// ---------------------------------------------------------------------------
// fused: 5 sub-GEMMs (i, u, f0, f1, o) for the same 128 h-columns + in-register
// LSTM combine. grid = (B/128, HDIM/128).
// ---------------------------------------------------------------------------
__global__ __launch_bounds__(256, 2) void fused_cell(
    const short* __restrict__ A,      // xb: B x K bf16
    const short* __restrict__ Wb,     // 2560 x K bf16
    const float* __restrict__ chc,    // (2, B, H)
    const float* __restrict__ b_i,
    const float* __restrict__ b_o,
    const float* __restrict__ b_u,
    const float* __restrict__ fbias,
    float* __restrict__ out)          // [next_cell (B*H) | out (B*H)]
{
    __shared__ short As[128 * 32];   // 8 KB
    __shared__ short Bs[128 * 32];   // 8 KB

    const int t    = threadIdx.x;
    const int lane = t & 63;
    const int wave = t >> 6;
    const int wr   = wave >> 1;
    const int wc   = wave & 1;
    const int quad = lane >> 4;
    const int l16  = lane & 15;

    const int mBase = blockIdx.x * 128;
    const int hBase = blockIdx.y * 128;

    // staging segments
    const int s0 = t, s1 = t + 256;
    const int r0 = s0 >> 2, c0s = (s0 & 3) * 8;
    const int r1 = s1 >> 2, c1s = (s1 & 3) * 8;

    const short* Arow0 = A + (size_t)(mBase + r0) * KDIM + c0s;
    const short* Arow1 = A + (size_t)(mBase + r1) * KDIM + c1s;

    // per-lane h columns for frag j: h = hBase + wc*64 + j*16 + l16
    float bi[4], bo[4], bu[4], fb[4];
#pragma unroll
    for (int j = 0; j < 4; ++j) {
        int h = hBase + wc * 64 + j * 16 + l16;
        bi[j] = b_i[h]; bo[j] = b_o[h]; bu[j] = b_u[h]; fb[j] = fbias[h];
    }

    f32x4 acc[4][4];
    float ncell[4][4][4];

    // ---- pass 1: gate i (g=0) ----
    {
        const short* Bt = Wb + (size_t)(0 * HDIM + hBase) * KDIM;
        run_gemm_pass(Arow0, Arow1, Bt + (size_t)r0 * KDIM + c0s, Bt + (size_t)r1 * KDIM + c1s,
                      As, Bs, s0, s1, wr, wc, quad, l16, acc);
#pragma unroll
        for (int i = 0; i < 4; ++i)
#pragma unroll
            for (int j = 0; j < 4; ++j)
#pragma unroll
                for (int r = 0; r < 4; ++r)
                    ncell[i][j][r] = fast_sigmoid(acc[i][j][r] + bi[j]);
    }
    // ---- pass 2: gate u (g=2) ----
    {
        const short* Bt = Wb + (size_t)(2 * HDIM + hBase) * KDIM;
        run_gemm_pass(Arow0, Arow1, Bt + (size_t)r0 * KDIM + c0s, Bt + (size_t)r1 * KDIM + c1s,
                      As, Bs, s0, s1, wr, wc, quad, l16, acc);
#pragma unroll
        for (int i = 0; i < 4; ++i)
#pragma unroll
            for (int j = 0; j < 4; ++j)
#pragma unroll
                for (int r = 0; r < 4; ++r)
                    ncell[i][j][r] *= fast_tanh(acc[i][j][r] + bu[j]);
    }
    // ---- pass 3: gate f0 (g=3) ----
    {
        const short* Bt = Wb + (size_t)(3 * HDIM + hBase) * KDIM;
        run_gemm_pass(Arow0, Arow1, Bt + (size_t)r0 * KDIM + c0s, Bt + (size_t)r1 * KDIM + c1s,
                      As, Bs, s0, s1, wr, wc, quad, l16, acc);
#pragma unroll
        for (int i = 0; i < 4; ++i) {
            int m0 = mBase + wr * 64 + i * 16 + quad * 4;
#pragma unroll
            for (int j = 0; j < 4; ++j) {
                int h = hBase + wc * 64 + j * 16 + l16;
#pragma unroll
                for (int r = 0; r < 4; ++r) {
                    float c0v = chc[(size_t)(m0 + r) * HDIM + h];
                    ncell[i][j][r] += (fast_sigmoid(acc[i][j][r]) + fb[j]) * c0v;
                }
            }
        }
    }
    // ---- pass 4: gate f1 (g=4), write next_cell ----
    {
        const short* Bt = Wb + (size_t)(4 * HDIM + hBase) * KDIM;
        run_gemm_pass(Arow0, Arow1, Bt + (size_t)r0 * KDIM + c0s, Bt + (size_t)r1 * KDIM + c1s,
                      As, Bs, s0, s1, wr, wc, quad, l16, acc);
#pragma unroll
        for (int i = 0; i < 4; ++i) {
            int m0 = mBase + wr * 64 + i * 16 + quad * 4;
#pragma unroll
            for (int j = 0; j < 4; ++j) {
                int h = hBase + wc * 64 + j * 16 + l16;
#pragma unroll
                for (int r = 0; r < 4; ++r) {
                    float c1v = chc[(size_t)BROWS * HDIM + (size_t)(m0 + r) * HDIM + h];
                    float nc = ncell[i][j][r] + (fast_sigmoid(acc[i][j][r]) + fb[j]) * c1v;
                    ncell[i][j][r] = nc;
                    out[(size_t)(m0 + r) * HDIM + h] = nc;
                }
            }
        }
    }
    // ---- pass 5: gate o (g=1), write out ----
    {
        const short* Bt = Wb + (size_t)(1 * HDIM + hBase) * KDIM;
        run_gemm_pass(Arow0, Arow1, Bt + (size_t)r0 * KDIM + c0s, Bt + (size_t)r1 * KDIM + c1s,
                      As, Bs, s0, s1, wr, wc, quad, l16, acc);
#pragma unroll
        for (int i = 0; i < 4; ++i) {
            int m0 = mBase + wr * 64 + i * 16 + quad * 4;
#pragma unroll
            for (int j = 0; j < 4; ++j) {
                int h = hBase + wc * 64 + j * 16 + l16;
#pragma unroll
                for (int r = 0; r < 4; ++r) {
                    float og = fast_sigmoid(acc[i][j][r] + bo[j]);
                    out[(size_t)BROWS * HDIM + (size_t)(m0 + r) * HDIM + h] =
                        fast_tanh(og * ncell[i][j][r]);
                }
            }
        }
    }
}

// ---------------------------------------------------------------------------
extern "C" void kernel_launch(void* const* d_in, const int* in_sizes, int n_in,
                              void* d_out, int out_size, void* d_ws, size_t ws_size,
                              hipStream_t stream) {
    const float* label = (const float*)d_in[0];
    const float* chh   = (const float*)d_in[1];
    const float* chc   = (const float*)d_in[2];
    const float* W_i   = (const float*)d_in[3];
    const float* b_i   = (const float*)d_in[4];
    const float* W_o   = (const float*)d_in[5];
    const float* b_o   = (const float*)d_in[6];
    const float* W_u   = (const float*)d_in[7];
    const float* b_u   = (const float*)d_in[8];
    const float* W_fl  = (const float*)d_in[9];
    const float* W_fs  = (const float*)d_in[10];
    const float* fbias = (const float*)d_in[11];
    float* out = (float*)d_out;

    char* ws = (char*)d_ws;
    short* xb = (short*)ws;                  // B x K bf16
    short* Wb = (short*)(ws + XB_BYTES);     // 2560 x K bf16

    pack_x<<<(BROWS * (KDIM / 4)) / 256, 256, 0, stream>>>(label, chh, xb);
    pack_w<<<(NGATES * (KDIM / 4)) / 256, 256, 0, stream>>>(W_i, W_o, W_u, W_fl, W_fs, Wb);

    dim3 ggrid(BROWS / 128, HDIM / 128);     // 128 x 4 = 512 blocks
    fused_cell<<<ggrid, 256, 0, stream>>>(xb, Wb, chc, b_i, b_o, b_u, fbias, out);
}

// Round 3
// 336.082 us; speedup vs baseline: 1.3330x; 1.3330x over previous
//
#include <hip/hip_runtime.h>
#include <hip/hip_bf16.h>
#include <cstdint>
#include <cstddef>

// Problem constants (fixed by reference)
#define BROWS   16384
#define LDIM    128
#define HDIM    512
#define KDIM    1152            // LABEL_DIM + 2*H_DIM
#define NGATES  2560            // 5 * HDIM  (i, o, u, f0, f1)

// workspace layout (bytes)
#define XB_BYTES  ((size_t)BROWS * KDIM * 2)            // 37,748,736
#define WB_BYTES  ((size_t)NGATES * KDIM * 2)           //  5,898,240
// gates: BROWS * NGATES bf16 = 83,886,080

using f32x4   = __attribute__((ext_vector_type(4))) float;
using bfrag   = __attribute__((ext_vector_type(8))) short;   // 8 bf16 = 4 VGPRs

__device__ __forceinline__ short f2bf(float f) {
    union { float f; uint32_t u; } a; a.f = f;
    uint32_t u = a.u;
    uint32_t lsb = (u >> 16) & 1u;
    u += 0x7fffu + lsb;               // round-to-nearest-even
    return (short)(u >> 16);
}
__device__ __forceinline__ float bf2f(short s) {
    union { uint32_t u; float f; } a;
    a.u = ((uint32_t)(uint16_t)s) << 16;
    return a.f;
}

__device__ __forceinline__ void load_lds16(const void* g, void* l) {
    __builtin_amdgcn_global_load_lds(
        (const __attribute__((address_space(1))) void*)g,
        (__attribute__((address_space(3))) void*)l, 16, 0, 0);
}

__device__ __forceinline__ float fast_sigmoid(float x) {
    return 1.0f / (1.0f + __expf(-x));
}
__device__ __forceinline__ float fast_tanh(float x) {
    float t = __expf(2.0f * x);
    return 1.0f - 2.0f / (t + 1.0f);
}

// ---------------------------------------------------------------------------
// pack_all: one launch.
//   blocks [0, NBX): xb[b, :] = bf16([label[b,:] | h0[b,:] | h1[b,:]])
//   blocks [NBX, NBX+NBW): Wb row n = bf16 of the gate-n weight row
// 8 elements per thread: 2x float4 load -> 1x 16B bf16 store.
// ---------------------------------------------------------------------------
#define NBX  ((BROWS  * (KDIM / 8)) / 256)   // 9216
#define NBW  ((NGATES * (KDIM / 8)) / 256)   // 1440

__global__ __launch_bounds__(256) void pack_all(
    const float* __restrict__ label, const float* __restrict__ chh,
    const float* __restrict__ Wi, const float* __restrict__ Wo,
    const float* __restrict__ Wu, const float* __restrict__ Wfl,
    const float* __restrict__ Wfs,
    short* __restrict__ xb, short* __restrict__ Wb)
{
    const int perRow = KDIM / 8;  // 144
    int blk = blockIdx.x;
    const float* src;
    short* dst;
    if (blk < NBX) {
        int tid = blk * 256 + threadIdx.x;
        int b = tid / perRow;
        int d = (tid - b * perRow) * 8;
        if (d < LDIM) {
            src = label + (size_t)b * LDIM + d;
        } else {
            int dd = d - LDIM;
            int k  = dd >> 9;
            int j  = dd & 511;
            src = chh + ((size_t)k * BROWS + b) * HDIM + j;
        }
        dst = xb + (size_t)b * KDIM + d;
    } else {
        int tid = (blk - NBX) * 256 + threadIdx.x;
        int n = tid / perRow;
        int d = (tid - n * perRow) * 8;
        int g = n >> 9, h = n & 511;
        if (g == 0)      src = Wi + (size_t)h * KDIM + d;
        else if (g == 1) src = Wo + (size_t)h * KDIM + d;
        else if (g == 2) src = Wu + (size_t)h * KDIM + d;
        else {
            int k = g - 3;
            if (d < LDIM) {
                src = Wfl + (size_t)h * LDIM + d;
            } else {
                int dd = d - LDIM;
                int j  = dd >> 9;
                int jj = dd & 511;
                src = Wfs + (((size_t)(k * 2 + j) * HDIM + h) * HDIM) + jj;
            }
        }
        dst = Wb + (size_t)n * KDIM + d;
    }
    float4 v0 = *(const float4*)src;
    float4 v1 = *(const float4*)(src + 4);
    bfrag s;
    s[0] = f2bf(v0.x); s[1] = f2bf(v0.y); s[2] = f2bf(v0.z); s[3] = f2bf(v0.w);
    s[4] = f2bf(v1.x); s[5] = f2bf(v1.y); s[6] = f2bf(v1.z); s[7] = f2bf(v1.w);
    *(bfrag*)dst = s;
}

// ---------------------------------------------------------------------------
// gemm_bt: C[m,n] = sum_k A[m,k] * Bt[n,k]  — m97 structure, unchanged from R1
// ---------------------------------------------------------------------------
__global__ __launch_bounds__(256) void gemm_bt(const short* __restrict__ A,
                                               const short* __restrict__ Bt,
                                               short* __restrict__ C) {
    __shared__ short As[128 * 32];   // 8 KB
    __shared__ short Bs[128 * 32];   // 8 KB

    const int t    = threadIdx.x;
    const int lane = t & 63;
    const int wave = t >> 6;
    const int wr   = wave >> 1;
    const int wc   = wave & 1;
    const int quad = lane >> 4;
    const int l16  = lane & 15;

    const int mBase = blockIdx.x * 128;
    const int nBase = blockIdx.y * 128;

    f32x4 acc[4][4] = {};

    const int s0 = t, s1 = t + 256;
    const int r0 = s0 >> 2, c0 = (s0 & 3) * 8;
    const int r1 = s1 >> 2, c1 = (s1 & 3) * 8;

    const short* Arow0 = A + (size_t)(mBase + r0) * KDIM + c0;
    const short* Arow1 = A + (size_t)(mBase + r1) * KDIM + c1;
    const short* Brow0 = Bt + (size_t)(nBase + r0) * KDIM + c0;
    const short* Brow1 = Bt + (size_t)(nBase + r1) * KDIM + c1;

    for (int k0 = 0; k0 < KDIM; k0 += 32) {
        load_lds16(Arow0 + k0, As + s0 * 8);
        load_lds16(Arow1 + k0, As + s1 * 8);
        load_lds16(Brow0 + k0, Bs + s0 * 8);
        load_lds16(Brow1 + k0, Bs + s1 * 8);
        __syncthreads();

        bfrag a[4], b[4];
#pragma unroll
        for (int i = 0; i < 4; ++i) {
            a[i] = *(const bfrag*)(As + (wr * 64 + i * 16 + l16) * 32 + quad * 8);
            b[i] = *(const bfrag*)(Bs + (wc * 64 + i * 16 + l16) * 32 + quad * 8);
        }
#pragma unroll
        for (int i = 0; i < 4; ++i)
#pragma unroll
            for (int j = 0; j < 4; ++j)
                acc[i][j] = __builtin_amdgcn_mfma_f32_16x16x32_bf16(a[i], b[j], acc[i][j], 0, 0, 0);
        __syncthreads();
    }

#pragma unroll
    for (int i = 0; i < 4; ++i) {
        int m0 = mBase + wr * 64 + i * 16 + quad * 4;
#pragma unroll
        for (int j = 0; j < 4; ++j) {
            int n = nBase + wc * 64 + j * 16 + l16;
#pragma unroll
            for (int r = 0; r < 4; ++r) {
                C[(size_t)(m0 + r) * NGATES + n] = f2bf(acc[i][j][r]);
            }
        }
    }
}

// ---------------------------------------------------------------------------
// epilogue: gates (B x 2560 bf16 logits) -> next_cell, out (fp32).
// 8 h-columns per thread: each gate read is one 16B bfrag, chc/out via float4.
// ---------------------------------------------------------------------------
__global__ __launch_bounds__(256) void epilogue(const short* __restrict__ gates,
                                                const float* __restrict__ chc,
                                                const float* __restrict__ b_i,
                                                const float* __restrict__ b_o,
                                                const float* __restrict__ b_u,
                                                const float* __restrict__ fbias,
                                                float* __restrict__ out) {
    int tid = blockIdx.x * 256 + threadIdx.x;     // over B * (H/8)
    int b  = tid >> 6;                            // H/8 = 64 per row
    int h8 = (tid & 63) << 3;

    const short* g = gates + (size_t)b * NGATES + h8;
    bfrag vi  = *(const bfrag*)(g);
    bfrag vo  = *(const bfrag*)(g + HDIM);
    bfrag vu  = *(const bfrag*)(g + 2 * HDIM);
    bfrag vf0 = *(const bfrag*)(g + 3 * HDIM);
    bfrag vf1 = *(const bfrag*)(g + 4 * HDIM);

    float4 bi0 = *(const float4*)(b_i + h8),   bi1 = *(const float4*)(b_i + h8 + 4);
    float4 bo0 = *(const float4*)(b_o + h8),   bo1 = *(const float4*)(b_o + h8 + 4);
    float4 bu0 = *(const float4*)(b_u + h8),   bu1 = *(const float4*)(b_u + h8 + 4);
    float4 fb0 = *(const float4*)(fbias + h8), fb1 = *(const float4*)(fbias + h8 + 4);

    size_t cbase = (size_t)b * HDIM + h8;
    float4 c00 = *(const float4*)(chc + cbase);
    float4 c01 = *(const float4*)(chc + cbase + 4);
    float4 c10 = *(const float4*)(chc + (size_t)BROWS * HDIM + cbase);
    float4 c11 = *(const float4*)(chc + (size_t)BROWS * HDIM + cbase + 4);

    float bi[8] = {bi0.x,bi0.y,bi0.z,bi0.w, bi1.x,bi1.y,bi1.z,bi1.w};
    float bo[8] = {bo0.x,bo0.y,bo0.z,bo0.w, bo1.x,bo1.y,bo1.z,bo1.w};
    float bu[8] = {bu0.x,bu0.y,bu0.z,bu0.w, bu1.x,bu1.y,bu1.z,bu1.w};
    float fb[8] = {fb0.x,fb0.y,fb0.z,fb0.w, fb1.x,fb1.y,fb1.z,fb1.w};
    float c0[8] = {c00.x,c00.y,c00.z,c00.w, c01.x,c01.y,c01.z,c01.w};
    float c1[8] = {c10.x,c10.y,c10.z,c10.w, c11.x,c11.y,c11.z,c11.w};

    float nc[8], ou[8];
#pragma unroll
    for (int e = 0; e < 8; ++e) {
        float ig = fast_sigmoid(bf2f(vi[e]) + bi[e]);
        float og = fast_sigmoid(bf2f(vo[e]) + bo[e]);
        float uu = fast_tanh(bf2f(vu[e]) + bu[e]);
        float f0 = fast_sigmoid(bf2f(vf0[e]));
        float f1 = fast_sigmoid(bf2f(vf1[e]));
        float ncell = ig * uu + f0 * c0[e] + f1 * c1[e] + fb[e] * (c0[e] + c1[e]);
        nc[e] = ncell;
        ou[e] = fast_tanh(og * ncell);
    }
    float4 n0 = {nc[0], nc[1], nc[2], nc[3]}, n1 = {nc[4], nc[5], nc[6], nc[7]};
    float4 o0 = {ou[0], ou[1], ou[2], ou[3]}, o1 = {ou[4], ou[5], ou[6], ou[7]};
    *(float4*)(out + cbase)     = n0;
    *(float4*)(out + cbase + 4) = n1;
    *(float4*)(out + (size_t)BROWS * HDIM + cbase)     = o0;
    *(float4*)(out + (size_t)BROWS * HDIM + cbase + 4) = o1;
}

// ---------------------------------------------------------------------------
extern "C" void kernel_launch(void* const* d_in, const int* in_sizes, int n_in,
                              void* d_out, int out_size, void* d_ws, size_t ws_size,
                              hipStream_t stream) {
    const float* label = (const float*)d_in[0];
    const float* chh   = (const float*)d_in[1];
    const float* chc   = (const float*)d_in[2];
    const float* W_i   = (const float*)d_in[3];
    const float* b_i   = (const float*)d_in[4];
    const float* W_o   = (const float*)d_in[5];
    const float* b_o   = (const float*)d_in[6];
    const float* W_u   = (const float*)d_in[7];
    const float* b_u   = (const float*)d_in[8];
    const float* W_fl  = (const float*)d_in[9];
    const float* W_fs  = (const float*)d_in[10];
    const float* fbias = (const float*)d_in[11];
    float* out = (float*)d_out;

    char* ws = (char*)d_ws;
    short* xb    = (short*)ws;                          // B x K bf16
    short* Wb    = (short*)(ws + XB_BYTES);             // 2560 x K bf16
    short* gates = (short*)(ws + XB_BYTES + WB_BYTES);  // B x 2560 bf16

    pack_all<<<NBX + NBW, 256, 0, stream>>>(label, chh, W_i, W_o, W_u, W_fl, W_fs, xb, Wb);

    dim3 ggrid(BROWS / 128, NGATES / 128);
    gemm_bt<<<ggrid, 256, 0, stream>>>(xb, Wb, gates);

    epilogue<<<(BROWS * (HDIM / 8)) / 256, 256, 0, stream>>>(gates, chc, b_i, b_o, b_u, fbias, out);
}

// Round 4
// 330.451 us; speedup vs baseline: 1.3557x; 1.0170x over previous
//
#include <hip/hip_runtime.h>
#include <hip/hip_bf16.h>
#include <cstdint>
#include <cstddef>

// Problem constants (fixed by reference)
#define BROWS   16384
#define LDIM    128
#define HDIM    512
#define KDIM    1152            // LABEL_DIM + 2*H_DIM
#define NGATES  2560            // 5 * HDIM  (i, o, u, f0, f1)

// workspace layout (bytes)
#define XB_BYTES  ((size_t)BROWS * KDIM * 2)            // 37,748,736
#define WB_BYTES  ((size_t)NGATES * KDIM * 2)           //  5,898,240
// gates: BROWS * NGATES bf16 = 83,886,080

using f32x4   = __attribute__((ext_vector_type(4))) float;
using bfrag   = __attribute__((ext_vector_type(8))) short;   // 8 bf16 = 4 VGPRs

__device__ __forceinline__ short f2bf(float f) {
    union { float f; uint32_t u; } a; a.f = f;
    uint32_t u = a.u;
    uint32_t lsb = (u >> 16) & 1u;
    u += 0x7fffu + lsb;               // round-to-nearest-even
    return (short)(u >> 16);
}
__device__ __forceinline__ float bf2f(short s) {
    union { uint32_t u; float f; } a;
    a.u = ((uint32_t)(uint16_t)s) << 16;
    return a.f;
}

__device__ __forceinline__ void load_lds16(const void* g, void* l) {
    __builtin_amdgcn_global_load_lds(
        (const __attribute__((address_space(1))) void*)g,
        (__attribute__((address_space(3))) void*)l, 16, 0, 0);
}

__device__ __forceinline__ float fast_sigmoid(float x) {
    return 1.0f / (1.0f + __expf(-x));
}
__device__ __forceinline__ float fast_tanh(float x) {
    float t = __expf(2.0f * x);
    return 1.0f - 2.0f / (t + 1.0f);
}

// ---------------------------------------------------------------------------
// pack_all: one launch.
//   blocks [0, NBX): xb[b, :] = bf16([label[b,:] | h0[b,:] | h1[b,:]])
//   blocks [NBX, NBX+NBW): Wb row n = bf16 of the gate-n weight row
// 8 elements per thread: 2x float4 load -> 1x 16B bf16 store.
// ---------------------------------------------------------------------------
#define NBX  ((BROWS  * (KDIM / 8)) / 256)   // 9216
#define NBW  ((NGATES * (KDIM / 8)) / 256)   // 1440

__global__ __launch_bounds__(256) void pack_all(
    const float* __restrict__ label, const float* __restrict__ chh,
    const float* __restrict__ Wi, const float* __restrict__ Wo,
    const float* __restrict__ Wu, const float* __restrict__ Wfl,
    const float* __restrict__ Wfs,
    short* __restrict__ xb, short* __restrict__ Wb)
{
    const int perRow = KDIM / 8;  // 144
    int blk = blockIdx.x;
    const float* src;
    short* dst;
    if (blk < NBX) {
        int tid = blk * 256 + threadIdx.x;
        int b = tid / perRow;
        int d = (tid - b * perRow) * 8;
        if (d < LDIM) {
            src = label + (size_t)b * LDIM + d;
        } else {
            int dd = d - LDIM;
            int k  = dd >> 9;
            int j  = dd & 511;
            src = chh + ((size_t)k * BROWS + b) * HDIM + j;
        }
        dst = xb + (size_t)b * KDIM + d;
    } else {
        int tid = (blk - NBX) * 256 + threadIdx.x;
        int n = tid / perRow;
        int d = (tid - n * perRow) * 8;
        int g = n >> 9, h = n & 511;
        if (g == 0)      src = Wi + (size_t)h * KDIM + d;
        else if (g == 1) src = Wo + (size_t)h * KDIM + d;
        else if (g == 2) src = Wu + (size_t)h * KDIM + d;
        else {
            int k = g - 3;
            if (d < LDIM) {
                src = Wfl + (size_t)h * LDIM + d;
            } else {
                int dd = d - LDIM;
                int j  = dd >> 9;
                int jj = dd & 511;
                src = Wfs + (((size_t)(k * 2 + j) * HDIM + h) * HDIM) + jj;
            }
        }
        dst = Wb + (size_t)n * KDIM + d;
    }
    float4 v0 = *(const float4*)src;
    float4 v1 = *(const float4*)(src + 4);
    bfrag s;
    s[0] = f2bf(v0.x); s[1] = f2bf(v0.y); s[2] = f2bf(v0.z); s[3] = f2bf(v0.w);
    s[4] = f2bf(v1.x); s[5] = f2bf(v1.y); s[6] = f2bf(v1.z); s[7] = f2bf(v1.w);
    *(bfrag*)dst = s;
}

// ---------------------------------------------------------------------------
// gemm_bt: C[m,n] = sum_k A[m,k] * Bt[n,k]  — m97 structure with:
//  * __launch_bounds__(256,4): force V<=64 so V+AGPR(64) <= 128 -> 4 waves/SIMD
//  * XOR column swizzle on LDS staging: slot (row, cphys) holds global column
//    segment (cphys ^ (row&3)). Staging LDS addresses stay lane-linear
//    (global_load_lds requirement); fragment reads use
//    row*32 + ((quad ^ (row&3))*8) — spreads the 16 l16-lanes over all 8
//    4-bank groups -> 2 lanes/group (free) instead of 8-way conflicts.
// ---------------------------------------------------------------------------
__global__ __launch_bounds__(256, 4) void gemm_bt(const short* __restrict__ A,
                                                  const short* __restrict__ Bt,
                                                  short* __restrict__ C) {
    __shared__ short As[128 * 32];   // 8 KB
    __shared__ short Bs[128 * 32];   // 8 KB

    const int t    = threadIdx.x;
    const int lane = t & 63;
    const int wave = t >> 6;
    const int wr   = wave >> 1;
    const int wc   = wave & 1;
    const int quad = lane >> 4;
    const int l16  = lane & 15;

    const int mBase = blockIdx.x * 128;
    const int nBase = blockIdx.y * 128;

    f32x4 acc[4][4] = {};

    // staging: slot s holds (row = s>>2, physical colseg = s&3), sourced from
    // global colseg (s&3) ^ (row&3)
    const int s0 = t, s1 = t + 256;
    const int r0 = s0 >> 2, c0 = ((s0 & 3) ^ (r0 & 3)) * 8;
    const int r1 = s1 >> 2, c1 = ((s1 & 3) ^ (r1 & 3)) * 8;

    const short* Arow0 = A + (size_t)(mBase + r0) * KDIM + c0;
    const short* Arow1 = A + (size_t)(mBase + r1) * KDIM + c1;
    const short* Brow0 = Bt + (size_t)(nBase + r0) * KDIM + c0;
    const short* Brow1 = Bt + (size_t)(nBase + r1) * KDIM + c1;

    // fragment LDS offsets (loop-invariant, swizzled)
    int aOff[4], bOff[4];
#pragma unroll
    for (int i = 0; i < 4; ++i) {
        int rowA = wr * 64 + i * 16 + l16;
        aOff[i] = rowA * 32 + ((quad ^ (rowA & 3)) * 8);
        int rowB = wc * 64 + i * 16 + l16;
        bOff[i] = rowB * 32 + ((quad ^ (rowB & 3)) * 8);
    }

    for (int k0 = 0; k0 < KDIM; k0 += 32) {
        load_lds16(Arow0 + k0, As + s0 * 8);
        load_lds16(Arow1 + k0, As + s1 * 8);
        load_lds16(Brow0 + k0, Bs + s0 * 8);
        load_lds16(Brow1 + k0, Bs + s1 * 8);
        __syncthreads();

        bfrag a[4], b[4];
#pragma unroll
        for (int i = 0; i < 4; ++i) {
            a[i] = *(const bfrag*)(As + aOff[i]);
            b[i] = *(const bfrag*)(Bs + bOff[i]);
        }
#pragma unroll
        for (int i = 0; i < 4; ++i)
#pragma unroll
            for (int j = 0; j < 4; ++j)
                acc[i][j] = __builtin_amdgcn_mfma_f32_16x16x32_bf16(a[i], b[j], acc[i][j], 0, 0, 0);
        __syncthreads();
    }

#pragma unroll
    for (int i = 0; i < 4; ++i) {
        int m0 = mBase + wr * 64 + i * 16 + quad * 4;
#pragma unroll
        for (int j = 0; j < 4; ++j) {
            int n = nBase + wc * 64 + j * 16 + l16;
#pragma unroll
            for (int r = 0; r < 4; ++r) {
                C[(size_t)(m0 + r) * NGATES + n] = f2bf(acc[i][j][r]);
            }
        }
    }
}

// ---------------------------------------------------------------------------
// epilogue: gates (B x 2560 bf16 logits) -> next_cell, out (fp32).
// 8 h-columns per thread: each gate read is one 16B bfrag, chc/out via float4.
// ---------------------------------------------------------------------------
__global__ __launch_bounds__(256) void epilogue(const short* __restrict__ gates,
                                                const float* __restrict__ chc,
                                                const float* __restrict__ b_i,
                                                const float* __restrict__ b_o,
                                                const float* __restrict__ b_u,
                                                const float* __restrict__ fbias,
                                                float* __restrict__ out) {
    int tid = blockIdx.x * 256 + threadIdx.x;     // over B * (H/8)
    int b  = tid >> 6;                            // H/8 = 64 per row
    int h8 = (tid & 63) << 3;

    const short* g = gates + (size_t)b * NGATES + h8;
    bfrag vi  = *(const bfrag*)(g);
    bfrag vo  = *(const bfrag*)(g + HDIM);
    bfrag vu  = *(const bfrag*)(g + 2 * HDIM);
    bfrag vf0 = *(const bfrag*)(g + 3 * HDIM);
    bfrag vf1 = *(const bfrag*)(g + 4 * HDIM);

    float4 bi0 = *(const float4*)(b_i + h8),   bi1 = *(const float4*)(b_i + h8 + 4);
    float4 bo0 = *(const float4*)(b_o + h8),   bo1 = *(const float4*)(b_o + h8 + 4);
    float4 bu0 = *(const float4*)(b_u + h8),   bu1 = *(const float4*)(b_u + h8 + 4);
    float4 fb0 = *(const float4*)(fbias + h8), fb1 = *(const float4*)(fbias + h8 + 4);

    size_t cbase = (size_t)b * HDIM + h8;
    float4 c00 = *(const float4*)(chc + cbase);
    float4 c01 = *(const float4*)(chc + cbase + 4);
    float4 c10 = *(const float4*)(chc + (size_t)BROWS * HDIM + cbase);
    float4 c11 = *(const float4*)(chc + (size_t)BROWS * HDIM + cbase + 4);

    float bi[8] = {bi0.x,bi0.y,bi0.z,bi0.w, bi1.x,bi1.y,bi1.z,bi1.w};
    float bo[8] = {bo0.x,bo0.y,bo0.z,bo0.w, bo1.x,bo1.y,bo1.z,bo1.w};
    float bu[8] = {bu0.x,bu0.y,bu0.z,bu0.w, bu1.x,bu1.y,bu1.z,bu1.w};
    float fb[8] = {fb0.x,fb0.y,fb0.z,fb0.w, fb1.x,fb1.y,fb1.z,fb1.w};
    float c0[8] = {c00.x,c00.y,c00.z,c00.w, c01.x,c01.y,c01.z,c01.w};
    float c1[8] = {c10.x,c10.y,c10.z,c10.w, c11.x,c11.y,c11.z,c11.w};

    float nc[8], ou[8];
#pragma unroll
    for (int e = 0; e < 8; ++e) {
        float ig = fast_sigmoid(bf2f(vi[e]) + bi[e]);
        float og = fast_sigmoid(bf2f(vo[e]) + bo[e]);
        float uu = fast_tanh(bf2f(vu[e]) + bu[e]);
        float f0 = fast_sigmoid(bf2f(vf0[e]));
        float f1 = fast_sigmoid(bf2f(vf1[e]));
        float ncell = ig * uu + f0 * c0[e] + f1 * c1[e] + fb[e] * (c0[e] + c1[e]);
        nc[e] = ncell;
        ou[e] = fast_tanh(og * ncell);
    }
    float4 n0 = {nc[0], nc[1], nc[2], nc[3]}, n1 = {nc[4], nc[5], nc[6], nc[7]};
    float4 o0 = {ou[0], ou[1], ou[2], ou[3]}, o1 = {ou[4], ou[5], ou[6], ou[7]};
    *(float4*)(out + cbase)     = n0;
    *(float4*)(out + cbase + 4) = n1;
    *(float4*)(out + (size_t)BROWS * HDIM + cbase)     = o0;
    *(float4*)(out + (size_t)BROWS * HDIM + cbase + 4) = o1;
}

// ---------------------------------------------------------------------------
extern "C" void kernel_launch(void* const* d_in, const int* in_sizes, int n_in,
                              void* d_out, int out_size, void* d_ws, size_t ws_size,
                              hipStream_t stream) {
    const float* label = (const float*)d_in[0];
    const float* chh   = (const float*)d_in[1];
    const float* chc   = (const float*)d_in[2];
    const float* W_i   = (const float*)d_in[3];
    const float* b_i   = (const float*)d_in[4];
    const float* W_o   = (const float*)d_in[5];
    const float* b_o   = (const float*)d_in[6];
    const float* W_u   = (const float*)d_in[7];
    const float* b_u   = (const float*)d_in[8];
    const float* W_fl  = (const float*)d_in[9];
    const float* W_fs  = (const float*)d_in[10];
    const float* fbias = (const float*)d_in[11];
    float* out = (float*)d_out;

    char* ws = (char*)d_ws;
    short* xb    = (short*)ws;                          // B x K bf16
    short* Wb    = (short*)(ws + XB_BYTES);             // 2560 x K bf16
    short* gates = (short*)(ws + XB_BYTES + WB_BYTES);  // B x 2560 bf16

    pack_all<<<NBX + NBW, 256, 0, stream>>>(label, chh, W_i, W_o, W_u, W_fl, W_fs, xb, Wb);

    dim3 ggrid(BROWS / 128, NGATES / 128);
    gemm_bt<<<ggrid, 256, 0, stream>>>(xb, Wb, gates);

    epilogue<<<(BROWS * (HDIM / 8)) / 256, 256, 0, stream>>>(gates, chc, b_i, b_o, b_u, fbias, out);
}